// Round 1
// baseline (627.516 us; speedup 1.0000x reference)
//
#include <hip/hip_runtime.h>
#include <hip/hip_bf16.h>
#include <math.h>

// Problem constants (match reference)
#define BATCH 8192
#define FEAT  1024
#define DLAT  128            // D
#define DP1   129            // D+1

// ---------------------------------------------------------------------------
// Kernel A: theta = x @ W + b   (fp32, strict k-order accumulation)
// grid = BATCH/32 = 256 blocks, 256 threads; each block: 32 rows x 128 cols
// ---------------------------------------------------------------------------
#define TILE_M 32
#define KT     32

__global__ __launch_bounds__(256) void gemm_theta(
    const float* __restrict__ x, const float* __restrict__ W,
    const float* __restrict__ b, float* __restrict__ theta) {
  __shared__ __align__(16) float xs[TILE_M][KT];     // 4 KB
  __shared__ __align__(16) float wsh[KT][DLAT];      // 16 KB
  const int row0 = blockIdx.x * TILE_M;
  const int t = threadIdx.x;
  const int c4 = (t & 31) * 4;   // col base (4 consecutive cols)
  const int r4 = (t >> 5) * 4;   // row base (4 consecutive rows)
  float acc[4][4] = {{0.f}};

  for (int k0 = 0; k0 < FEAT; k0 += KT) {
    // x tile: 32x32 floats = 256 float4 -> 1 per thread
    {
      const int r  = t >> 3;          // 0..31
      const int cq = (t & 7) * 4;     // 0..28
      *(float4*)&xs[r][cq] =
          *(const float4*)(x + (size_t)(row0 + r) * FEAT + k0 + cq);
    }
    // W tile: 32x128 floats = 1024 float4 -> 4 per thread
    #pragma unroll
    for (int i = 0; i < 4; ++i) {
      const int idx = t + i * 256;
      const int kk  = idx >> 5;       // 0..31
      const int cq  = (idx & 31) * 4; // 0..124
      *(float4*)&wsh[kk][cq] =
          *(const float4*)(W + (size_t)(k0 + kk) * DLAT + cq);
    }
    __syncthreads();
    #pragma unroll
    for (int kk = 0; kk < KT; ++kk) {
      float xv[4];
      #pragma unroll
      for (int r = 0; r < 4; ++r) xv[r] = xs[r4 + r][kk];
      const float4 w4 = *(const float4*)&wsh[kk][c4];
      const float wv[4] = {w4.x, w4.y, w4.z, w4.w};
      #pragma unroll
      for (int r = 0; r < 4; ++r)
        #pragma unroll
        for (int c = 0; c < 4; ++c)
          acc[r][c] = fmaf(xv[r], wv[c], acc[r][c]);
    }
    __syncthreads();
  }
  const float4 bv = *(const float4*)(b + c4);
  #pragma unroll
  for (int r = 0; r < 4; ++r) {
    float4 o;
    o.x = acc[r][0] + bv.x;
    o.y = acc[r][1] + bv.y;
    o.z = acc[r][2] + bv.z;
    o.w = acc[r][3] + bv.w;
    *(float4*)(theta + (size_t)(row0 + r4 + r) * DLAT + c4) = o;
  }
}

// ---------------------------------------------------------------------------
// Kernel B: per-row clip, bitonic sort (desc), distr/support/entropy-partial,
//           and the 129x128 sample write (fully coalesced float4 stores).
// grid = BATCH blocks, 256 threads.
// ---------------------------------------------------------------------------
__global__ __launch_bounds__(256) void smap_rows(
    const float* __restrict__ theta, float* __restrict__ sample,
    float* __restrict__ distr, float* __restrict__ support,
    float* __restrict__ entpart) {
  __shared__ __align__(16) float mu[DLAT];
  __shared__ __align__(16) float s[DLAT];
  __shared__ float red[256];
  __shared__ int   redi[256];
  const int row = blockIdx.x;
  const int t = threadIdx.x;

  if (t < DLAT) {
    float v = theta[(size_t)row * DLAT + t];
    v = fminf(fmaxf(v, 0.0f), 1.0f);   // SparseMAP marginals
    mu[t] = v;
    s[t]  = v;
  }
  __syncthreads();

  // Bitonic sort s[0..127] descending (threads 0..127 active)
  for (int k = 2; k <= DLAT; k <<= 1) {
    for (int j = k >> 1; j > 0; j >>= 1) {
      if (t < DLAT) {
        const int ixj = t ^ j;
        if (ixj > t) {
          const float a = s[t], bq = s[ixj];
          const bool up = ((t & k) == 0);
          const bool sw = up ? (a < bq) : (a > bq);
          if (sw) { s[t] = bq; s[ixj] = a; }
        }
      }
      __syncthreads();
    }
  }

  // distr + entropy partial + support
  float w = 0.0f; int pos = 0; float ent = 0.0f;
  if (t < DP1) {
    if (t == 0)          w = 1.0f - s[0];
    else if (t < DLAT)   w = s[t - 1] - s[t];
    else                 w = s[DLAT - 1];
    distr[(size_t)row * DP1 + t] = w;
    if (w > 0.0f) { pos = 1; ent = -w * logf(w); }
  }
  red[t] = ent; redi[t] = pos;
  __syncthreads();
  for (int off = 128; off > 0; off >>= 1) {
    if (t < off) { red[t] += red[t + off]; redi[t] += redi[t + off]; }
    __syncthreads();
  }
  if (t == 0) {
    entpart[row] = red[0];
    support[row] = (float)redi[0];
  }

  // sample: row 0 = zeros; row j (1..128) = (mu >= s[j-1]) ? 1 : 0
  const int jl = t >> 5;          // 0..7: config-row lane
  const int cq = (t & 31) * 4;    // col base
  float4* out = (float4*)(sample + (size_t)row * DP1 * DLAT);
  const float4 m4 = *(const float4*)&mu[cq];
  for (int jb = 0; jb < 136; jb += 8) {
    const int j = jb + jl;
    if (j < DP1) {
      const float thr = (j == 0) ? 2.0f : s[j - 1];
      float4 o;
      o.x = (m4.x >= thr) ? 1.0f : 0.0f;
      o.y = (m4.y >= thr) ? 1.0f : 0.0f;
      o.z = (m4.z >= thr) ? 1.0f : 0.0f;
      o.w = (m4.w >= thr) ? 1.0f : 0.0f;
      out[(size_t)j * (DLAT / 4) + (cq >> 2)] = o;
    }
  }
}

// ---------------------------------------------------------------------------
// Kernel C: deterministic reduction of per-row entropy partials, /B
// ---------------------------------------------------------------------------
__global__ __launch_bounds__(256) void reduce_ent(
    const float* __restrict__ entpart, float* __restrict__ outent) {
  __shared__ double red[256];
  const int t = threadIdx.x;
  double acc = 0.0;
  for (int i = t; i < BATCH; i += 256) acc += (double)entpart[i];
  red[t] = acc;
  __syncthreads();
  for (int off = 128; off > 0; off >>= 1) {
    if (t < off) red[t] += red[t + off];
    __syncthreads();
  }
  if (t == 0) *outent = (float)(red[0] / (double)BATCH);
}

// ---------------------------------------------------------------------------
extern "C" void kernel_launch(void* const* d_in, const int* in_sizes, int n_in,
                              void* d_out, int out_size, void* d_ws, size_t ws_size,
                              hipStream_t stream) {
  const float* x = (const float*)d_in[0];   // [B, F]
  const float* W = (const float*)d_in[1];   // [F, D]
  const float* b = (const float*)d_in[2];   // [D]

  float* out = (float*)d_out;
  // Output layout (flat, return order): sample, distr, entropy, support
  const size_t n_sample = (size_t)BATCH * DP1 * DLAT;   // 135,266,304
  const size_t n_distr  = (size_t)BATCH * DP1;          //   1,056,768
  float* sample  = out;
  float* distr   = out + n_sample;
  float* entropy = out + n_sample + n_distr;
  float* support = out + n_sample + n_distr + 1;

  // Workspace: theta [B, D] fp32, then entropy partials [B]
  float* theta   = (float*)d_ws;
  float* entpart = theta + (size_t)BATCH * DLAT;

  gemm_theta<<<BATCH / TILE_M, 256, 0, stream>>>(x, W, b, theta);
  smap_rows<<<BATCH, 256, 0, stream>>>(theta, sample, distr, support, entpart);
  reduce_ent<<<1, 256, 0, stream>>>(entpart, entropy);
}

// Round 5
// 622.006 us; speedup vs baseline: 1.0089x; 1.0089x over previous
//
#include <hip/hip_runtime.h>
#include <hip/hip_bf16.h>
#include <math.h>

// Problem constants (match reference)
#define BATCH 8192
#define FEAT  1024
#define DLAT  128            // D
#define DP1   129            // D+1

typedef float f32x4 __attribute__((ext_vector_type(4)));  // nontemporal-compatible

// ---------------------------------------------------------------------------
// Kernel A: theta = x @ W + b   (fp32, strict k-order accumulation)
// grid = BATCH/32 = 256 blocks, 256 threads; each block: 32 rows x 128 cols.
// Double-buffered LDS, global->reg prefetch, float4 LDS reads (kk step 4).
// Accumulation order per output element identical (k ascending) to the r1
// kernel that passed -> bitwise-stable theta.
// ---------------------------------------------------------------------------
#define TILE_M 32
#define KT     32
#define NK0    (FEAT / KT)   // 32 k-tiles

__global__ __launch_bounds__(256) void gemm_theta(
    const float* __restrict__ x, const float* __restrict__ W,
    const float* __restrict__ b, float* __restrict__ theta) {
  __shared__ __align__(16) float xs[2][TILE_M][KT];   // 8 KB
  __shared__ __align__(16) float wsh[2][KT][DLAT];    // 32 KB
  const int row0 = blockIdx.x * TILE_M;
  const int t = threadIdx.x;
  const int c4 = (t & 31) * 4;   // col base (4 consecutive cols)
  const int r4 = (t >> 5) * 4;   // row base (4 consecutive rows)

  // per-thread load coords
  const int lxr = t >> 3;            // 0..31 (x row)
  const int lxc = (t & 7) * 4;       // 0..28 (x k-offset)
  float acc[4][4] = {{0.f}};

  // prologue: tile 0 -> LDS buf 0
  {
    float4 px = *(const float4*)(x + (size_t)(row0 + lxr) * FEAT + lxc);
    *(float4*)&xs[0][lxr][lxc] = px;
    #pragma unroll
    for (int i = 0; i < 4; ++i) {
      const int idx = t + i * 256;
      const int kk  = idx >> 5;
      const int cq  = (idx & 31) * 4;
      *(float4*)&wsh[0][kk][cq] = *(const float4*)(W + (size_t)kk * DLAT + cq);
    }
  }
  __syncthreads();

  int buf = 0;
  for (int k0it = 0; k0it < NK0; ++k0it) {
    // prefetch next k-tile into registers (hidden under FMAs below)
    float4 px;
    float4 pw[4];
    const bool hasNext = (k0it + 1 < NK0);
    if (hasNext) {
      const int k0n = (k0it + 1) * KT;
      px = *(const float4*)(x + (size_t)(row0 + lxr) * FEAT + k0n + lxc);
      #pragma unroll
      for (int i = 0; i < 4; ++i) {
        const int idx = t + i * 256;
        const int kk  = idx >> 5;
        const int cq  = (idx & 31) * 4;
        pw[i] = *(const float4*)(W + (size_t)(k0n + kk) * DLAT + cq);
      }
    }

    // compute current tile: float4 LDS reads, kk in steps of 4
    #pragma unroll
    for (int kk = 0; kk < KT; kk += 4) {
      float4 xv[4], wv[4];
      #pragma unroll
      for (int r = 0; r < 4; ++r) xv[r] = *(const float4*)&xs[buf][r4 + r][kk];
      #pragma unroll
      for (int i = 0; i < 4; ++i) wv[i] = *(const float4*)&wsh[buf][kk + i][c4];
      #pragma unroll
      for (int r = 0; r < 4; ++r) {
        const float* xr = (const float*)&xv[r];
        #pragma unroll
        for (int i = 0; i < 4; ++i) {
          const float* wc = (const float*)&wv[i];
          #pragma unroll
          for (int c = 0; c < 4; ++c)
            acc[r][c] = fmaf(xr[i], wc[c], acc[r][c]);
        }
      }
    }

    // stage prefetched regs into the other buffer
    if (hasNext) {
      *(float4*)&xs[buf ^ 1][lxr][lxc] = px;
      #pragma unroll
      for (int i = 0; i < 4; ++i) {
        const int idx = t + i * 256;
        const int kk  = idx >> 5;
        const int cq  = (idx & 31) * 4;
        *(float4*)&wsh[buf ^ 1][kk][cq] = pw[i];
      }
    }
    __syncthreads();
    buf ^= 1;
  }

  const float4 bv = *(const float4*)(b + c4);
  #pragma unroll
  for (int r = 0; r < 4; ++r) {
    float4 o;
    o.x = acc[r][0] + bv.x;
    o.y = acc[r][1] + bv.y;
    o.z = acc[r][2] + bv.z;
    o.w = acc[r][3] + bv.w;
    *(float4*)(theta + (size_t)(row0 + r4 + r) * DLAT + c4) = o;
  }
}

// ---------------------------------------------------------------------------
// Kernel B: per-row clip, rank-and-scatter stable descending sort (barrier-
//           separated read/write phases -> no cross-lane ordering hazards),
//           distr/support/entropy-partial, 129x128 sample write (nt float4).
// grid = BATCH blocks, 256 threads.
// ---------------------------------------------------------------------------
__global__ __launch_bounds__(256) void smap_rows(
    const float* __restrict__ theta, float* __restrict__ sample,
    float* __restrict__ distr, float* __restrict__ support,
    float* __restrict__ entpart) {
  __shared__ __align__(16) float mu[DLAT];
  __shared__ __align__(16) float s[DLAT];
  __shared__ float red[256];
  __shared__ int   redi[256];
  const int row = blockIdx.x;
  const int t = threadIdx.x;

  if (t < DLAT) {
    float v = theta[(size_t)row * DLAT + t];
    v = fminf(fmaxf(v, 0.0f), 1.0f);   // SparseMAP marginals
    mu[t] = v;
  }
  __syncthreads();

  // Stable descending sort via rank-and-scatter. rank(t) = #elements that
  // sort before mu[t]: strictly greater, or equal with smaller index.
  // Unique ranks -> s is a permutation of mu = exact -sort(-mu) values.
  // All reads of mu[] precede the barrier-protected writes of s[] -> no
  // unsynchronized LDS read-after-write anywhere (r4 bug fix).
  if (t < DLAT) {
    const float v = mu[t];
    int rank = 0;
    #pragma unroll
    for (int q = 0; q < DLAT / 4; ++q) {
      const float4 m4 = *(const float4*)&mu[q * 4];
      rank += (m4.x > v || (m4.x == v && (q * 4 + 0) < t)) ? 1 : 0;
      rank += (m4.y > v || (m4.y == v && (q * 4 + 1) < t)) ? 1 : 0;
      rank += (m4.z > v || (m4.z == v && (q * 4 + 2) < t)) ? 1 : 0;
      rank += (m4.w > v || (m4.w == v && (q * 4 + 3) < t)) ? 1 : 0;
    }
    s[rank] = v;
  }
  __syncthreads();

  // distr + entropy partial + support
  float w = 0.0f; int pos = 0; float ent = 0.0f;
  if (t < DP1) {
    if (t == 0)          w = 1.0f - s[0];
    else if (t < DLAT)   w = s[t - 1] - s[t];
    else                 w = s[DLAT - 1];
    distr[(size_t)row * DP1 + t] = w;
    if (w > 0.0f) { pos = 1; ent = -w * logf(w); }
  }
  red[t] = ent; redi[t] = pos;
  __syncthreads();
  for (int off = 128; off > 0; off >>= 1) {
    if (t < off) { red[t] += red[t + off]; redi[t] += redi[t + off]; }
    __syncthreads();
  }
  if (t == 0) {
    entpart[row] = red[0];
    support[row] = (float)redi[0];
  }

  // sample: row 0 = zeros; row j (1..128) = (mu >= s[j-1]) ? 1 : 0
  // 8 config-rows in flight (256 thr = 8 x 32-lane col groups) -> each
  // iteration stores 4 KB contiguous. Nontemporal: pure streaming output.
  const int jl = t >> 5;          // 0..7: config-row lane
  const int cq = (t & 31) * 4;    // col base
  f32x4* out = (f32x4*)(sample + (size_t)row * DP1 * DLAT);
  const float4 m4 = *(const float4*)&mu[cq];
  #pragma unroll
  for (int it = 0; it < 16; ++it) {
    const int j = it * 8 + jl;    // 0..127
    const float thr = (j == 0) ? 2.0f : s[j - 1];
    f32x4 o;
    o.x = (m4.x >= thr) ? 1.0f : 0.0f;
    o.y = (m4.y >= thr) ? 1.0f : 0.0f;
    o.z = (m4.z >= thr) ? 1.0f : 0.0f;
    o.w = (m4.w >= thr) ? 1.0f : 0.0f;
    __builtin_nontemporal_store(o, &out[(size_t)j * (DLAT / 4) + (cq >> 2)]);
  }
  if (jl == 0) {                  // j = 128
    const float thr = s[DLAT - 1];
    f32x4 o;
    o.x = (m4.x >= thr) ? 1.0f : 0.0f;
    o.y = (m4.y >= thr) ? 1.0f : 0.0f;
    o.z = (m4.z >= thr) ? 1.0f : 0.0f;
    o.w = (m4.w >= thr) ? 1.0f : 0.0f;
    __builtin_nontemporal_store(o, &out[(size_t)DLAT * (DLAT / 4) + (cq >> 2)]);
  }
}

// ---------------------------------------------------------------------------
// Kernel C: deterministic reduction of per-row entropy partials, /B
// ---------------------------------------------------------------------------
__global__ __launch_bounds__(1024) void reduce_ent(
    const float* __restrict__ entpart, float* __restrict__ outent) {
  __shared__ double red[1024];
  const int t = threadIdx.x;
  double acc = 0.0;
  for (int i = t; i < BATCH; i += 1024) acc += (double)entpart[i];
  red[t] = acc;
  __syncthreads();
  for (int off = 512; off > 0; off >>= 1) {
    if (t < off) red[t] += red[t + off];
    __syncthreads();
  }
  if (t == 0) *outent = (float)(red[0] / (double)BATCH);
}

// ---------------------------------------------------------------------------
extern "C" void kernel_launch(void* const* d_in, const int* in_sizes, int n_in,
                              void* d_out, int out_size, void* d_ws, size_t ws_size,
                              hipStream_t stream) {
  const float* x = (const float*)d_in[0];   // [B, F]
  const float* W = (const float*)d_in[1];   // [F, D]
  const float* b = (const float*)d_in[2];   // [D]

  float* out = (float*)d_out;
  // Output layout (flat, return order): sample, distr, entropy, support
  const size_t n_sample = (size_t)BATCH * DP1 * DLAT;   // 135,266,304
  const size_t n_distr  = (size_t)BATCH * DP1;          //   1,056,768
  float* sample  = out;
  float* distr   = out + n_sample;
  float* entropy = out + n_sample + n_distr;
  float* support = out + n_sample + n_distr + 1;

  // Workspace: theta [B, D] fp32, then entropy partials [B]
  float* theta   = (float*)d_ws;
  float* entpart = theta + (size_t)BATCH * DLAT;

  gemm_theta<<<BATCH / TILE_M, 256, 0, stream>>>(x, W, b, theta);
  smap_rows<<<BATCH, 256, 0, stream>>>(theta, sample, distr, support, entpart);
  reduce_ent<<<1, 1024, 0, stream>>>(entpart, entropy);
}